// Round 4
// baseline (307.371 us; speedup 1.0000x reference)
//
#include <hip/hip_runtime.h>

#define N_IN   128
#define LAYERS 6
#define N_H    320
#define DEG    32
#define N_OUT  18
#define N_TOTAL (N_IN + LAYERS * N_H)       // 2048
#define BB     8                            // batch elements per block
#define N_HID_UNITS (LAYERS * N_H)          // 1920
#define N_UNITS (N_HID_UNITS + N_OUT)       // 1938

typedef _Float16 half2_t __attribute__((ext_vector_type(2)));
typedef _Float16 half8_t __attribute__((ext_vector_type(8)));

#if __has_builtin(__builtin_amdgcn_fdot2)
#define FDOT2(a, b, c) __builtin_amdgcn_fdot2((a), (b), (c), false)
#else
__device__ __forceinline__ float fdot2_sw(half2_t a, half2_t b, float c) {
    return c + (float)a[0] * (float)b[0] + (float)a[1] * (float)b[1];
}
#define FDOT2(a, b, c) fdot2_sw((a), (b), (c))
#endif

__device__ __forceinline__ float fast_tanh(float x) {
    float e = __expf(2.0f * x);
    return 1.0f - 2.0f * __builtin_amdgcn_rcpf(e + 1.0f);
}

__device__ __forceinline__ unsigned comp(uint4 v, int k) {
    return k == 0 ? v.x : k == 1 ? v.y : k == 2 ? v.z : v.w;
}

// fused table per unit: dwords [0..15] = offset pairs (idx*16 | idx*16 << 16),
//                       dwords [16..31] = weight half2 pairs
__global__ __launch_bounds__(64) void pack_kernel(
    const int* __restrict__ hid_src, const float* __restrict__ hid_w,
    const int* __restrict__ out_src, const float* __restrict__ out_w,
    unsigned int* __restrict__ fused)
{
    int u = blockIdx.x * 64 + threadIdx.x;
    if (u >= N_UNITS) return;
    const int*   src;
    const float* w;
    if (u < N_HID_UNITS) { src = hid_src + u * DEG;                 w = hid_w + u * DEG; }
    else                 { src = out_src + (u - N_HID_UNITS) * DEG; w = out_w + (u - N_HID_UNITS) * DEG; }
    unsigned int* dst = fused + u * 32;
    for (int q = 0; q < 16; ++q) {
        unsigned o0 = (unsigned)src[2 * q]     << 4;   // byte offset, 16B rows
        unsigned o1 = (unsigned)src[2 * q + 1] << 4;
        dst[q] = o0 | (o1 << 16);
        half2_t wp;
        wp[0] = (_Float16)w[2 * q];
        wp[1] = (_Float16)w[2 * q + 1];
        dst[16 + q] = __builtin_bit_cast(unsigned int, wp);
    }
}

// Gather-dot for one unit over BB=8 batch elems; taps processed in pairs via
// v_perm (pair batch elem across the two gathered rows) + v_dot2_f32_f16.
__device__ __forceinline__ void gather_dot(const unsigned char* sA, const uint4 f[8],
                                           float acc[BB]) {
    #pragma unroll
    for (int p = 0; p < 16; ++p) {
        unsigned od = comp(f[p >> 2], p & 3);
        unsigned wd = comp(f[4 + (p >> 2)], p & 3);
        unsigned off0 = od & 0xffffu;
        unsigned off1 = od >> 16;
        uint4 g0 = *(const uint4*)(sA + off0);
        uint4 g1 = *(const uint4*)(sA + off1);
        half2_t wp = __builtin_bit_cast(half2_t, wd);
        #pragma unroll
        for (int k = 0; k < 4; ++k) {
            unsigned d0 = comp(g0, k), d1 = comp(g1, k);
            unsigned plo = __builtin_amdgcn_perm(d1, d0, 0x05040100u);  // (g0.lo16, g1.lo16)
            unsigned phi = __builtin_amdgcn_perm(d1, d0, 0x07060302u);  // (g0.hi16, g1.hi16)
            acc[2 * k]     = FDOT2(__builtin_bit_cast(half2_t, plo), wp, acc[2 * k]);
            acc[2 * k + 1] = FDOT2(__builtin_bit_cast(half2_t, phi), wp, acc[2 * k + 1]);
        }
    }
}

__global__ __launch_bounds__(N_H, 6) void policy_kernel(
    const float* __restrict__ obs,       // [B][N_IN]
    const uint4* __restrict__ ftab,      // [N_UNITS][8] fused offsets+weights
    const float* __restrict__ hid_b,     // [L][N_H]
    const float* __restrict__ out_b,     // [N_OUT]
    float*       __restrict__ out)       // [B][N_OUT]
{
    // acts row r = 8 x f16 (one per batch elem), 16 B -> one ds_read_b128 per gather
    __shared__ alignas(16) unsigned char sA[N_TOTAL * 16];   // 32 KB

    const int tid = threadIdx.x;
    const int b0  = blockIdx.x * BB;
    const int n   = tid;

    uint4 f[8];
    #pragma unroll
    for (int q = 0; q < 8; ++q) f[q] = ftab[n * 8 + q];

    if (tid < N_IN) {
        half8_t hv;
        #pragma unroll
        for (int j = 0; j < BB; ++j) hv[j] = (_Float16)obs[(b0 + j) * N_IN + tid];
        *(half8_t*)(sA + tid * 16) = hv;
    }
    __syncthreads();

    for (int l = 0; l < LAYERS; ++l) {
        float acc[BB] = {0.f, 0.f, 0.f, 0.f, 0.f, 0.f, 0.f, 0.f};
        gather_dot(sA, f, acc);

        // prefetch next layer's (or output layer's) fused table
        int nu = (l + 1 < LAYERS) ? ((l + 1) * N_H + n)
                                  : (N_HID_UNITS + (n < N_OUT ? n : 0));
        #pragma unroll
        for (int q = 0; q < 8; ++q) f[q] = ftab[nu * 8 + q];

        float bias = hid_b[l * N_H + n];
        half8_t hv;
        #pragma unroll
        for (int j = 0; j < BB; ++j) hv[j] = (_Float16)fast_tanh(acc[j] + bias);
        // this layer writes rows it never reads; one barrier per layer suffices
        *(half8_t*)(sA + (N_IN + l * N_H + n) * 16) = hv;
        __syncthreads();
    }

    if (n < N_OUT) {
        float acc[BB] = {0.f, 0.f, 0.f, 0.f, 0.f, 0.f, 0.f, 0.f};
        gather_dot(sA, f, acc);
        float bias = out_b[n];
        #pragma unroll
        for (int j = 0; j < BB; ++j)
            out[(b0 + j) * N_OUT + n] = fast_tanh(acc[j] + bias);
    }
}

extern "C" void kernel_launch(void* const* d_in, const int* in_sizes, int n_in,
                              void* d_out, int out_size, void* d_ws, size_t ws_size,
                              hipStream_t stream) {
    const float* obs     = (const float*)d_in[0];
    const int*   hid_src = (const int*)  d_in[1];
    const float* hid_w   = (const float*)d_in[2];
    const float* hid_b   = (const float*)d_in[3];
    const int*   out_src = (const int*)  d_in[4];
    const float* out_w   = (const float*)d_in[5];
    const float* out_b   = (const float*)d_in[6];
    float* out = (float*)d_out;
    unsigned int* fused = (unsigned int*)d_ws;   // 1938*32*4 = 248 KB

    const int batch = in_sizes[0] / N_IN;   // 8192

    pack_kernel<<<(N_UNITS + 63) / 64, 64, 0, stream>>>(
        hid_src, hid_w, out_src, out_w, fused);
    policy_kernel<<<batch / BB, N_H, 0, stream>>>(
        obs, (const uint4*)fused, hid_b, out_b, out);
}

// Round 5
// 104.495 us; speedup vs baseline: 2.9415x; 2.9415x over previous
//
#include <hip/hip_runtime.h>

#define N_IN   128
#define LAYERS 6
#define N_H    320
#define DEG    32
#define N_OUT  18
#define N_TOTAL (N_IN + LAYERS * N_H)       // 2048
#define BB     8                            // batch elements per block
#define N_HID_UNITS (LAYERS * N_H)          // 1920
#define N_UNITS (N_HID_UNITS + N_OUT)       // 1938

typedef _Float16 half2_t __attribute__((ext_vector_type(2)));
typedef _Float16 half8_t __attribute__((ext_vector_type(8)));

#if __has_builtin(__builtin_amdgcn_fdot2)
#define FDOT2(a, b, c) __builtin_amdgcn_fdot2((a), (b), (c), false)
#else
__device__ __forceinline__ float fdot2_sw(half2_t a, half2_t b, float c) {
    return c + (float)a[0] * (float)b[0] + (float)a[1] * (float)b[1];
}
#define FDOT2(a, b, c) fdot2_sw((a), (b), (c))
#endif

__device__ __forceinline__ float fast_tanh(float x) {
    float e = __expf(2.0f * x);
    return 1.0f - 2.0f * __builtin_amdgcn_rcpf(e + 1.0f);
}

// fused table per unit (32 dwords): [0..15] = offset pairs (idx0*16 | idx1*16<<16),
//                                   [16..31] = weight half2 pairs
__global__ __launch_bounds__(64) void pack_kernel(
    const int* __restrict__ hid_src, const float* __restrict__ hid_w,
    const int* __restrict__ out_src, const float* __restrict__ out_w,
    unsigned int* __restrict__ fused)
{
    int u = blockIdx.x * 64 + threadIdx.x;
    if (u >= N_UNITS) return;
    const int*   src;
    const float* w;
    if (u < N_HID_UNITS) { src = hid_src + u * DEG;                 w = hid_w + u * DEG; }
    else                 { src = out_src + (u - N_HID_UNITS) * DEG; w = out_w + (u - N_HID_UNITS) * DEG; }
    unsigned int* dst = fused + u * 32;
    for (int q = 0; q < 16; ++q) {
        unsigned o0 = (unsigned)src[2 * q]     << 4;   // byte offset into 16B rows
        unsigned o1 = (unsigned)src[2 * q + 1] << 4;
        dst[q] = o0 | (o1 << 16);
        half2_t wp;
        wp[0] = (_Float16)w[2 * q];
        wp[1] = (_Float16)w[2 * q + 1];
        dst[16 + q] = __builtin_bit_cast(unsigned int, wp);
    }
}

// One tap-pair: gather two 16B rows (8 f16 batch elems each), pair per-batch
// across the rows with v_perm, 2 MACs/instr via v_dot2_f32_f16.
// Everything is named scalars — nothing can fall to scratch.
#define DOT_STEP(OD, WD) do {                                              \
    unsigned _off0 = (OD) & 0xffffu;                                       \
    unsigned _off1 = (OD) >> 16;                                           \
    uint4 _g0 = *(const uint4*)(sA + _off0);                               \
    uint4 _g1 = *(const uint4*)(sA + _off1);                               \
    half2_t _wp = __builtin_bit_cast(half2_t, (WD));                       \
    unsigned _p0 = __builtin_amdgcn_perm(_g1.x, _g0.x, 0x05040100u);       \
    unsigned _p1 = __builtin_amdgcn_perm(_g1.x, _g0.x, 0x07060302u);       \
    unsigned _p2 = __builtin_amdgcn_perm(_g1.y, _g0.y, 0x05040100u);       \
    unsigned _p3 = __builtin_amdgcn_perm(_g1.y, _g0.y, 0x07060302u);       \
    unsigned _p4 = __builtin_amdgcn_perm(_g1.z, _g0.z, 0x05040100u);       \
    unsigned _p5 = __builtin_amdgcn_perm(_g1.z, _g0.z, 0x07060302u);       \
    unsigned _p6 = __builtin_amdgcn_perm(_g1.w, _g0.w, 0x05040100u);       \
    unsigned _p7 = __builtin_amdgcn_perm(_g1.w, _g0.w, 0x07060302u);       \
    acc0 = FDOT2(__builtin_bit_cast(half2_t, _p0), _wp, acc0);             \
    acc1 = FDOT2(__builtin_bit_cast(half2_t, _p1), _wp, acc1);             \
    acc2 = FDOT2(__builtin_bit_cast(half2_t, _p2), _wp, acc2);             \
    acc3 = FDOT2(__builtin_bit_cast(half2_t, _p3), _wp, acc3);             \
    acc4 = FDOT2(__builtin_bit_cast(half2_t, _p4), _wp, acc4);             \
    acc5 = FDOT2(__builtin_bit_cast(half2_t, _p5), _wp, acc5);             \
    acc6 = FDOT2(__builtin_bit_cast(half2_t, _p6), _wp, acc6);             \
    acc7 = FDOT2(__builtin_bit_cast(half2_t, _p7), _wp, acc7);             \
} while (0)

// Load the unit's fused table (8 x uint4, L2-hot) and run 16 tap-pairs.
#define GATHER_UNIT(BASE) do {                                             \
    const uint4* _t = ftab + (BASE);                                       \
    uint4 _fo0 = _t[0], _fo1 = _t[1], _fo2 = _t[2], _fo3 = _t[3];          \
    uint4 _fw0 = _t[4], _fw1 = _t[5], _fw2 = _t[6], _fw3 = _t[7];          \
    DOT_STEP(_fo0.x, _fw0.x); DOT_STEP(_fo0.y, _fw0.y);                    \
    DOT_STEP(_fo0.z, _fw0.z); DOT_STEP(_fo0.w, _fw0.w);                    \
    DOT_STEP(_fo1.x, _fw1.x); DOT_STEP(_fo1.y, _fw1.y);                    \
    DOT_STEP(_fo1.z, _fw1.z); DOT_STEP(_fo1.w, _fw1.w);                    \
    DOT_STEP(_fo2.x, _fw2.x); DOT_STEP(_fo2.y, _fw2.y);                    \
    DOT_STEP(_fo2.z, _fw2.z); DOT_STEP(_fo2.w, _fw2.w);                    \
    DOT_STEP(_fo3.x, _fw3.x); DOT_STEP(_fo3.y, _fw3.y);                    \
    DOT_STEP(_fo3.z, _fw3.z); DOT_STEP(_fo3.w, _fw3.w);                    \
} while (0)

__global__ __launch_bounds__(N_H, 5) void policy_kernel(
    const float* __restrict__ obs,       // [B][N_IN]
    const uint4* __restrict__ ftab,      // [N_UNITS][8] fused offsets+weights
    const float* __restrict__ hid_b,     // [L][N_H]
    const float* __restrict__ out_b,     // [N_OUT]
    float*       __restrict__ out)       // [B][N_OUT]
{
    // acts row r = 8 x f16 (one per batch elem) = 16 B -> one ds_read_b128/gather
    __shared__ alignas(16) unsigned char sA[N_TOTAL * 16];   // 32 KB

    const int tid = threadIdx.x;
    const int b0  = blockIdx.x * BB;
    const int n   = tid;

    if (tid < N_IN) {
        half8_t hv;
        #pragma unroll
        for (int j = 0; j < BB; ++j) hv[j] = (_Float16)obs[(b0 + j) * N_IN + tid];
        *(half8_t*)(sA + tid * 16) = hv;
    }
    __syncthreads();

    for (int l = 0; l < LAYERS; ++l) {
        float acc0 = 0.f, acc1 = 0.f, acc2 = 0.f, acc3 = 0.f;
        float acc4 = 0.f, acc5 = 0.f, acc6 = 0.f, acc7 = 0.f;
        GATHER_UNIT((l * N_H + n) * 8);

        float bias = hid_b[l * N_H + n];
        half8_t hv;
        hv[0] = (_Float16)fast_tanh(acc0 + bias);
        hv[1] = (_Float16)fast_tanh(acc1 + bias);
        hv[2] = (_Float16)fast_tanh(acc2 + bias);
        hv[3] = (_Float16)fast_tanh(acc3 + bias);
        hv[4] = (_Float16)fast_tanh(acc4 + bias);
        hv[5] = (_Float16)fast_tanh(acc5 + bias);
        hv[6] = (_Float16)fast_tanh(acc6 + bias);
        hv[7] = (_Float16)fast_tanh(acc7 + bias);
        // this layer writes rows it never reads; one barrier per layer suffices
        *(half8_t*)(sA + (N_IN + l * N_H + n) * 16) = hv;
        __syncthreads();
    }

    if (n < N_OUT) {
        float acc0 = 0.f, acc1 = 0.f, acc2 = 0.f, acc3 = 0.f;
        float acc4 = 0.f, acc5 = 0.f, acc6 = 0.f, acc7 = 0.f;
        GATHER_UNIT((N_HID_UNITS + n) * 8);
        float bias = out_b[n];
        out[(b0 + 0) * N_OUT + n] = fast_tanh(acc0 + bias);
        out[(b0 + 1) * N_OUT + n] = fast_tanh(acc1 + bias);
        out[(b0 + 2) * N_OUT + n] = fast_tanh(acc2 + bias);
        out[(b0 + 3) * N_OUT + n] = fast_tanh(acc3 + bias);
        out[(b0 + 4) * N_OUT + n] = fast_tanh(acc4 + bias);
        out[(b0 + 5) * N_OUT + n] = fast_tanh(acc5 + bias);
        out[(b0 + 6) * N_OUT + n] = fast_tanh(acc6 + bias);
        out[(b0 + 7) * N_OUT + n] = fast_tanh(acc7 + bias);
    }
}

extern "C" void kernel_launch(void* const* d_in, const int* in_sizes, int n_in,
                              void* d_out, int out_size, void* d_ws, size_t ws_size,
                              hipStream_t stream) {
    const float* obs     = (const float*)d_in[0];
    const int*   hid_src = (const int*)  d_in[1];
    const float* hid_w   = (const float*)d_in[2];
    const float* hid_b   = (const float*)d_in[3];
    const int*   out_src = (const int*)  d_in[4];
    const float* out_w   = (const float*)d_in[5];
    const float* out_b   = (const float*)d_in[6];
    float* out = (float*)d_out;
    unsigned int* fused = (unsigned int*)d_ws;   // 1938*32*4 = 248 KB

    const int batch = in_sizes[0] / N_IN;   // 8192

    pack_kernel<<<(N_UNITS + 63) / 64, 64, 0, stream>>>(
        hid_src, hid_w, out_src, out_w, fused);
    policy_kernel<<<batch / BB, N_H, 0, stream>>>(
        obs, (const uint4*)fused, hid_b, out_b, out);
}